// Round 11
// baseline (80.159 us; speedup 1.0000x reference)
//
#include <hip/hip_runtime.h>
#include <math.h>

namespace {

constexpr int Hh = 112, Ww = 112, Cc = 64, Nn = 16;
constexpr int OHh = 56, OWw = 56;
constexpr int HW = Hh * Ww;            // 12544 = 49*256
constexpr int OP = OHh * OWw;          // 3136
constexpr int NP = Nn * OP;            // 50176
constexpr int NHW = Nn * HW;           // 200704 = 196*1024
constexpr float BN_EPS_F = 1e-5f;
constexpr float CLAMP_MIN_F = 1e-4f;
constexpr int NSTAT = 32;

// K1: direct-load conv, 1x4 pixel strip per lane — no LDS, no barriers.
// Window = 3 rows x 6 cols: per row one aligned float4 + 2 edge dwords
// -> 9 VMEM per 4 pixels per channel; 324 FMAs/iter of self-cover (~650
// issue-cyc) before the next window's vmcnt wait -> HBM latency covered
// in-wave. 1-deep register prefetch; channel split NSPLIT ways.
template <int NSPLIT>
__global__ __launch_bounds__(256) void conv_strip4_kernel(
    const float* __restrict__ x, const float* __restrict__ wgt,
    float* __restrict__ P /* [NSPLIT][9][NHW] */)
{
    constexpr int CHS = Cc / NSPLIT;               // channels per part
    constexpr int NBLK = NSPLIT * 196;
    constexpr int CPX = NBLK / 8;                  // blocks per XCD chunk

    const int tid = threadIdx.x;
    const int b = blockIdx.x;
    const int swz = (b & 7) * CPX + (b >> 3);      // XCD-contiguous chunks
    const int part = swz / 196;
    const int bid = swz - part * 196;

    const int s = bid * 256 + tid;                 // strip id; pixels 4s..4s+3
    const int pos0 = 4 * s;
    const int n = pos0 / HW;
    const int hw = pos0 - n * HW;
    const int h = hw / Ww;
    const int w0 = hw - h * Ww;                    // multiple of 4, 0..108

    const int hm = (h == 0) ? 1 : h - 1;
    const int hp = (h == Hh - 1) ? (Hh - 2) : (h + 1);
    const int wl = (w0 == 0) ? 1 : w0 - 1;
    const int wr = (w0 == Ww - 4) ? (Ww - 2) : (w0 + 4);

    const int ro[3] = { hm * Ww, h * Ww, hp * Ww };

    const float* xb = x + ((size_t)n * Cc + part * CHS) * HW;

    float4 m[3];                                   // cols w0..w0+3 (aligned)
    float el[3], er[3];                            // cols w0-1, w0+4 (reflected)
    float4 n_m[3];
    float n_el[3], n_er[3];
#pragma unroll
    for (int r = 0; r < 3; ++r) {
        m[r] = *(const float4*)(xb + ro[r] + w0);
        el[r] = xb[ro[r] + wl];
        er[r] = xb[ro[r] + wr];
    }

    float acc[4][9];
#pragma unroll
    for (int p = 0; p < 4; ++p)
#pragma unroll
        for (int k = 0; k < 9; ++k) acc[p][k] = 0.f;

#pragma unroll 2
    for (int c = 0; c < CHS; ++c) {
        // prefetch channel c+1 (wraps on last iter: in-bounds, unused)
        const float* xn = xb + (size_t)((c + 1) & (CHS - 1)) * HW;
#pragma unroll
        for (int r = 0; r < 3; ++r) {
            n_m[r] = *(const float4*)(xn + ro[r] + w0);
            n_el[r] = xn[ro[r] + wl];
            n_er[r] = xn[ro[r] + wr];
        }

        const int cg = part * CHS + c;
#pragma unroll
        for (int k = 0; k < 9; ++k) {
            const float* wk = wgt + ((size_t)k * Cc + cg) * 9;   // uniform -> s_load
#pragma unroll
            for (int r = 0; r < 3; ++r) {
                const float wa = wk[3 * r], wb = wk[3 * r + 1], wc = wk[3 * r + 2];
                acc[0][k] = fmaf(wa, el[r],  acc[0][k]);
                acc[0][k] = fmaf(wb, m[r].x, acc[0][k]);
                acc[0][k] = fmaf(wc, m[r].y, acc[0][k]);
                acc[1][k] = fmaf(wa, m[r].x, acc[1][k]);
                acc[1][k] = fmaf(wb, m[r].y, acc[1][k]);
                acc[1][k] = fmaf(wc, m[r].z, acc[1][k]);
                acc[2][k] = fmaf(wa, m[r].y, acc[2][k]);
                acc[2][k] = fmaf(wb, m[r].z, acc[2][k]);
                acc[2][k] = fmaf(wc, m[r].w, acc[2][k]);
                acc[3][k] = fmaf(wa, m[r].z, acc[3][k]);
                acc[3][k] = fmaf(wb, m[r].w, acc[3][k]);
                acc[3][k] = fmaf(wc, er[r],  acc[3][k]);
            }
        }

#pragma unroll
        for (int r = 0; r < 3; ++r) {
            m[r] = n_m[r]; el[r] = n_el[r]; er[r] = n_er[r];
        }
    }

    float* Ph = P + (size_t)part * 9 * NHW;
#pragma unroll
    for (int k = 0; k < 9; ++k)
        *(float4*)(Ph + (size_t)k * NHW + pos0) =
            make_float4(acc[0][k], acc[1][k], acc[2][k], acc[3][k]);
}

// K2: merge NSPLIT partials (float4/lane = 4 px), BN stats (spread atomics),
// extract even positions (aligned float2 stores).
template <int NSPLIT>
__global__ __launch_bounds__(256) void merge_stats_kernel(
    const float* __restrict__ P, double* __restrict__ stats,
    float* __restrict__ sig_even /* [9][NP] */)
{
    __shared__ float rs[4], rq[4];
    const int tid = threadIdx.x;
    const int k = blockIdx.y;
    const int p0 = (blockIdx.x * 256 + tid) * 4;   // NHW = 196*1024

    float4 v = *(const float4*)(P + (size_t)k * NHW + p0);
#pragma unroll
    for (int qq = 1; qq < NSPLIT; ++qq) {
        const float4 t = *(const float4*)(P + ((size_t)qq * 9 + k) * NHW + p0);
        v.x += t.x; v.y += t.y; v.z += t.z; v.w += t.w;
    }

    const int w = p0 % Ww;                         // multiple of 4
    const int h = (p0 / Ww) % Hh;
    const int n = p0 / HW;
    if (!(h & 1)) {
        *(float2*)(sig_even + (size_t)k * NP + n * OP + (h >> 1) * OWw + (w >> 1)) =
            make_float2(v.x, v.z);
    }

    float s = v.x + v.y + v.z + v.w;
    float q = v.x * v.x + v.y * v.y + v.z * v.z + v.w * v.w;
#pragma unroll
    for (int off = 32; off > 0; off >>= 1) {
        s += __shfl_down(s, off, 64);
        q += __shfl_down(q, off, 64);
    }
    const int lane = tid & 63, wv = tid >> 6;
    if (lane == 0) { rs[wv] = s; rq[wv] = q; }
    __syncthreads();
    if (tid == 0) {
        double* st = stats + (size_t)(blockIdx.x & (NSTAT - 1)) * 18;
        atomicAdd(&st[k], (double)(rs[0] + rs[1] + rs[2] + rs[3]));
        atomicAdd(&st[9 + k], (double)(rq[0] + rq[1] + rq[2] + rq[3]));
    }
}

// K3: fused normalize + apply. One block per (n, oh) row: BN+clamp+normalize
// the 56-wide sigma row ONCE into LDS, then 4 channels/pass x 16 passes.
__global__ __launch_bounds__(256) void apply_kernel(
    const float* __restrict__ x, const float* __restrict__ sig_raw,
    const float* __restrict__ gamma, const float* __restrict__ beta,
    const double* __restrict__ stats, float* __restrict__ out)
{
    __shared__ float srow[9][OWw];
    __shared__ float mean_s[9], istd_s[9], gb[18];

    const int tid = threadIdx.x;
    const int f = blockIdx.x;                      // 896 = 8*112
    const int fs = (f & 7) * 112 + (f >> 3);
    const int n = fs / OHh;
    const int oh = fs % OHh;

    if (tid < 9) {
        double s = 0.0, q = 0.0;
        for (int r = 0; r < NSTAT; ++r) { s += stats[r * 18 + tid]; q += stats[r * 18 + 9 + tid]; }
        const double cnt = (double)Nn * HW;
        const double m = s / cnt;
        const double v = q / cnt - m * m;
        mean_s[tid] = (float)m;
        istd_s[tid] = (float)(1.0 / sqrt(v + (double)BN_EPS_F));
        gb[tid] = gamma[tid];
        gb[9 + tid] = beta[tid];
    }
    __syncthreads();

    if (tid < OWw) {
        const int pp = n * OP + oh * OWw + tid;
        float s[9], ssum = 0.f;
#pragma unroll
        for (int k = 0; k < 9; ++k) {
            float v = fmaf((sig_raw[(size_t)k * NP + pp] - mean_s[k]) * istd_s[k], gb[k], gb[9 + k]);
            v = fmaxf(v, CLAMP_MIN_F);
            s[k] = v;
            ssum += v;
        }
        const float inv = 1.f / ssum;
#pragma unroll
        for (int k = 0; k < 9; ++k) srow[k][tid] = s[k] * inv;
    }
    __syncthreads();

    const int csub = tid >> 6;                     // wave-uniform channel sub-index
    const int lane = tid & 63;
    if (lane >= OWw) return;                       // no barriers after this point
    const int ow = lane;

    const int r0 = (oh == 0) ? 1 : (2 * oh - 1);
    const int r1 = 2 * oh, r2 = 2 * oh + 1;
    const int c0 = (ow == 0) ? 1 : (2 * ow - 1);
    const int c1 = 2 * ow, c2 = 2 * ow + 1;

    float sg[9];
#pragma unroll
    for (int k = 0; k < 9; ++k) sg[k] = srow[k][ow];

#pragma unroll 2
    for (int cc = 0; cc < 16; ++cc) {
        const int c = cc * 4 + csub;
        const float* xc = x + ((size_t)(n * Cc + c)) * HW;
        float o = 0.f;
        o = fmaf(sg[0], xc[r0 * Ww + c0], o);
        o = fmaf(sg[1], xc[r0 * Ww + c1], o);
        o = fmaf(sg[2], xc[r0 * Ww + c2], o);
        o = fmaf(sg[3], xc[r1 * Ww + c0], o);
        o = fmaf(sg[4], xc[r1 * Ww + c1], o);
        o = fmaf(sg[5], xc[r1 * Ww + c2], o);
        o = fmaf(sg[6], xc[r2 * Ww + c0], o);
        o = fmaf(sg[7], xc[r2 * Ww + c1], o);
        o = fmaf(sg[8], xc[r2 * Ww + c2], o);
        out[((size_t)(n * Cc + c)) * OP + oh * OWw + ow] = o;
    }
}

} // namespace

extern "C" void kernel_launch(void* const* d_in, const int* in_sizes, int n_in,
                              void* d_out, int out_size, void* d_ws, size_t ws_size,
                              hipStream_t stream) {
    const float* x     = (const float*)d_in[0];
    const float* wgt   = (const float*)d_in[1];
    const float* gamma = (const float*)d_in[2];
    const float* beta  = (const float*)d_in[3];
    float* out = (float*)d_out;

    double* stats = (double*)d_ws;                 // NSTAT*18 doubles = 4608 B
    float* P = (float*)((char*)d_ws + 8192);

    const size_t sig_bytes = (size_t)9 * NP * 4;   // 1.81 MB
    const size_t need4 = 8192 + (size_t)36 * NHW * 4 + sig_bytes;   // ~30.7 MB
    hipMemsetAsync(d_ws, 0, 8192, stream);

    if (ws_size >= need4) {
        float* sig_even = P + (size_t)36 * NHW;
        conv_strip4_kernel<4><<<784, 256, 0, stream>>>(x, wgt, P);
        merge_stats_kernel<4><<<dim3(196, 9), 256, 0, stream>>>(P, stats, sig_even);
        apply_kernel<<<896, 256, 0, stream>>>(x, sig_even, gamma, beta, stats, out);
    } else {
        float* sig_even = P + (size_t)18 * NHW;
        conv_strip4_kernel<2><<<392, 256, 0, stream>>>(x, wgt, P);
        merge_stats_kernel<2><<<dim3(196, 9), 256, 0, stream>>>(P, stats, sig_even);
        apply_kernel<<<896, 256, 0, stream>>>(x, sig_even, gamma, beta, stats, out);
    }
}

// Round 12
// 70.243 us; speedup vs baseline: 1.1412x; 1.1412x over previous
//
#include <hip/hip_runtime.h>
#include <math.h>

namespace {

constexpr int Hh = 112, Ww = 112, Cc = 64, Nn = 16;
constexpr int OHh = 56, OWw = 56;
constexpr int HW = Hh * Ww;            // 12544 = 49*256
constexpr int OP = OHh * OWw;          // 3136
constexpr int NP = Nn * OP;            // 50176
constexpr int NHW = Nn * HW;           // 200704 = 196*1024
constexpr float BN_EPS_F = 1e-5f;
constexpr float CLAMP_MIN_F = 1e-4f;
constexpr int NSTAT = 32;

struct WSet { float m0[3], m1[3], el[3], er[3]; };   // 3x4 window, 1x2 strip

__device__ __forceinline__ void load_set(WSet& s, const float* __restrict__ base,
                                         const int (&ro)[3], int w0, int wl, int wr) {
#pragma unroll
    for (int r = 0; r < 3; ++r) {
        const float2 f2 = *(const float2*)(base + ro[r] + w0);
        s.m0[r] = f2.x; s.m1[r] = f2.y;
        s.el[r] = base[ro[r] + wl];
        s.er[r] = base[ro[r] + wr];
    }
}

__device__ __forceinline__ void compute_set(const WSet& s, const float* __restrict__ wgt,
                                            int cg, float (&acc0)[9], float (&acc1)[9]) {
#pragma unroll
    for (int k = 0; k < 9; ++k) {
        const float* wk = wgt + ((size_t)k * Cc + cg) * 9;   // uniform -> s_load
#pragma unroll
        for (int r = 0; r < 3; ++r) {
            const float wa = wk[3 * r], wb = wk[3 * r + 1], wc = wk[3 * r + 2];
            acc0[k] = fmaf(wa, s.el[r], acc0[k]);
            acc0[k] = fmaf(wb, s.m0[r], acc0[k]);
            acc0[k] = fmaf(wc, s.m1[r], acc0[k]);
            acc1[k] = fmaf(wa, s.m0[r], acc1[k]);
            acc1[k] = fmaf(wb, s.m1[r], acc1[k]);
            acc1[k] = fmaf(wc, s.er[r], acc1[k]);
        }
    }
}

// K1: direct-load conv, 1x2 strip/lane, NO LDS/barriers, 2-DEEP register
// prefetch via 3 rotating compile-time-named sets: compute S[c%3], issue
// loads for c+2 into S[(c+2)%3]. Compiler emits counted vmcnt (keeps ~18
// loads in flight per wave) -> MLP tripled vs 1-deep.
template <int NSPLIT>
__global__ __launch_bounds__(256) void conv_2deep_kernel(
    const float* __restrict__ x, const float* __restrict__ wgt,
    float* __restrict__ P /* [NSPLIT][9][NHW] */)
{
    constexpr int CHS = Cc / NSPLIT;
    constexpr int NBLK = NSPLIT * 392;

    const int tid = threadIdx.x;
    const int b = blockIdx.x;
    const int swz = (b & 7) * (NBLK / 8) + (b >> 3);   // XCD-contiguous chunks
    const int part = swz / 392;
    const int bid = swz - part * 392;

    const int s = bid * 256 + tid;                 // strip id; pixels 2s, 2s+1
    const int pos0 = 2 * s;
    const int n = pos0 / HW;
    const int hw = pos0 - n * HW;
    const int h = hw / Ww;
    const int w0 = hw - h * Ww;                    // even, 0..110

    const int hm = (h == 0) ? 1 : h - 1;
    const int hp = (h == Hh - 1) ? (Hh - 2) : (h + 1);
    const int wl = (w0 == 0) ? 1 : w0 - 1;
    const int wr = (w0 == Ww - 2) ? (Ww - 2) : (w0 + 2);

    const int ro[3] = { hm * Ww, h * Ww, hp * Ww };

    const float* xb = x + ((size_t)n * Cc + part * CHS) * HW;

    float acc0[9], acc1[9];
#pragma unroll
    for (int k = 0; k < 9; ++k) { acc0[k] = 0.f; acc1[k] = 0.f; }

    WSet A, B, C;
    load_set(A, xb, ro, w0, wl, wr);
    load_set(B, xb + HW, ro, w0, wl, wr);

#define STEP(c, SC, SF)                                                          \
    if constexpr ((c) < CHS) {                                                   \
        if constexpr ((c) + 2 < CHS)                                             \
            load_set(SF, xb + (size_t)((c) + 2) * HW, ro, w0, wl, wr);           \
        compute_set(SC, wgt, part * CHS + (c), acc0, acc1);                      \
    }

    STEP(0,  A, C) STEP(1,  B, A) STEP(2,  C, B)
    STEP(3,  A, C) STEP(4,  B, A) STEP(5,  C, B)
    STEP(6,  A, C) STEP(7,  B, A) STEP(8,  C, B)
    STEP(9,  A, C) STEP(10, B, A) STEP(11, C, B)
    STEP(12, A, C) STEP(13, B, A) STEP(14, C, B)
    STEP(15, A, C) STEP(16, B, A) STEP(17, C, B)
    STEP(18, A, C) STEP(19, B, A) STEP(20, C, B)
    STEP(21, A, C) STEP(22, B, A) STEP(23, C, B)
    STEP(24, A, C) STEP(25, B, A) STEP(26, C, B)
    STEP(27, A, C) STEP(28, B, A) STEP(29, C, B)
    STEP(30, A, C) STEP(31, B, A)
#undef STEP

    float* Ph = P + (size_t)part * 9 * NHW;
#pragma unroll
    for (int k = 0; k < 9; ++k)
        *(float2*)(Ph + (size_t)k * NHW + pos0) = make_float2(acc0[k], acc1[k]);
}

// K2: merge NSPLIT partials (float4/lane = 4 px), BN stats (spread atomics),
// extract even positions (aligned float2 stores).
template <int NSPLIT>
__global__ __launch_bounds__(256) void merge_stats_kernel(
    const float* __restrict__ P, double* __restrict__ stats,
    float* __restrict__ sig_even /* [9][NP] */)
{
    __shared__ float rs[4], rq[4];
    const int tid = threadIdx.x;
    const int k = blockIdx.y;
    const int p0 = (blockIdx.x * 256 + tid) * 4;   // NHW = 196*1024

    float4 v = *(const float4*)(P + (size_t)k * NHW + p0);
#pragma unroll
    for (int qq = 1; qq < NSPLIT; ++qq) {
        const float4 t = *(const float4*)(P + ((size_t)qq * 9 + k) * NHW + p0);
        v.x += t.x; v.y += t.y; v.z += t.z; v.w += t.w;
    }

    const int w = p0 % Ww;                         // multiple of 4
    const int h = (p0 / Ww) % Hh;
    const int n = p0 / HW;
    if (!(h & 1)) {
        *(float2*)(sig_even + (size_t)k * NP + n * OP + (h >> 1) * OWw + (w >> 1)) =
            make_float2(v.x, v.z);
    }

    float s = v.x + v.y + v.z + v.w;
    float q = v.x * v.x + v.y * v.y + v.z * v.z + v.w * v.w;
#pragma unroll
    for (int off = 32; off > 0; off >>= 1) {
        s += __shfl_down(s, off, 64);
        q += __shfl_down(q, off, 64);
    }
    const int lane = tid & 63, wv = tid >> 6;
    if (lane == 0) { rs[wv] = s; rq[wv] = q; }
    __syncthreads();
    if (tid == 0) {
        double* st = stats + (size_t)(blockIdx.x & (NSTAT - 1)) * 18;
        atomicAdd(&st[k], (double)(rs[0] + rs[1] + rs[2] + rs[3]));
        atomicAdd(&st[9 + k], (double)(rq[0] + rq[1] + rq[2] + rq[3]));
    }
}

// K3: fused normalize + apply. One block per (n, oh) row: BN+clamp+normalize
// the 56-wide sigma row ONCE into LDS, then 4 channels/pass x 16 passes.
__global__ __launch_bounds__(256) void apply_kernel(
    const float* __restrict__ x, const float* __restrict__ sig_raw,
    const float* __restrict__ gamma, const float* __restrict__ beta,
    const double* __restrict__ stats, float* __restrict__ out)
{
    __shared__ float srow[9][OWw];
    __shared__ float mean_s[9], istd_s[9], gb[18];

    const int tid = threadIdx.x;
    const int f = blockIdx.x;                      // 896 = 8*112
    const int fs = (f & 7) * 112 + (f >> 3);
    const int n = fs / OHh;
    const int oh = fs % OHh;

    if (tid < 9) {
        double s = 0.0, q = 0.0;
        for (int r = 0; r < NSTAT; ++r) { s += stats[r * 18 + tid]; q += stats[r * 18 + 9 + tid]; }
        const double cnt = (double)Nn * HW;
        const double m = s / cnt;
        const double v = q / cnt - m * m;
        mean_s[tid] = (float)m;
        istd_s[tid] = (float)(1.0 / sqrt(v + (double)BN_EPS_F));
        gb[tid] = gamma[tid];
        gb[9 + tid] = beta[tid];
    }
    __syncthreads();

    if (tid < OWw) {
        const int pp = n * OP + oh * OWw + tid;
        float s[9], ssum = 0.f;
#pragma unroll
        for (int k = 0; k < 9; ++k) {
            float v = fmaf((sig_raw[(size_t)k * NP + pp] - mean_s[k]) * istd_s[k], gb[k], gb[9 + k]);
            v = fmaxf(v, CLAMP_MIN_F);
            s[k] = v;
            ssum += v;
        }
        const float inv = 1.f / ssum;
#pragma unroll
        for (int k = 0; k < 9; ++k) srow[k][tid] = s[k] * inv;
    }
    __syncthreads();

    const int csub = tid >> 6;                     // wave-uniform channel sub-index
    const int lane = tid & 63;
    if (lane >= OWw) return;                       // no barriers after this point
    const int ow = lane;

    const int r0 = (oh == 0) ? 1 : (2 * oh - 1);
    const int r1 = 2 * oh, r2 = 2 * oh + 1;
    const int c0 = (ow == 0) ? 1 : (2 * ow - 1);
    const int c1 = 2 * ow, c2 = 2 * ow + 1;

    float sg[9];
#pragma unroll
    for (int k = 0; k < 9; ++k) sg[k] = srow[k][ow];

#pragma unroll 2
    for (int cc = 0; cc < 16; ++cc) {
        const int c = cc * 4 + csub;
        const float* xc = x + ((size_t)(n * Cc + c)) * HW;
        float o = 0.f;
        o = fmaf(sg[0], xc[r0 * Ww + c0], o);
        o = fmaf(sg[1], xc[r0 * Ww + c1], o);
        o = fmaf(sg[2], xc[r0 * Ww + c2], o);
        o = fmaf(sg[3], xc[r1 * Ww + c0], o);
        o = fmaf(sg[4], xc[r1 * Ww + c1], o);
        o = fmaf(sg[5], xc[r1 * Ww + c2], o);
        o = fmaf(sg[6], xc[r2 * Ww + c0], o);
        o = fmaf(sg[7], xc[r2 * Ww + c1], o);
        o = fmaf(sg[8], xc[r2 * Ww + c2], o);
        out[((size_t)(n * Cc + c)) * OP + oh * OWw + ow] = o;
    }
}

} // namespace

extern "C" void kernel_launch(void* const* d_in, const int* in_sizes, int n_in,
                              void* d_out, int out_size, void* d_ws, size_t ws_size,
                              hipStream_t stream) {
    const float* x     = (const float*)d_in[0];
    const float* wgt   = (const float*)d_in[1];
    const float* gamma = (const float*)d_in[2];
    const float* beta  = (const float*)d_in[3];
    float* out = (float*)d_out;

    double* stats = (double*)d_ws;                 // NSTAT*18 doubles = 4608 B
    float* P = (float*)((char*)d_ws + 8192);

    const size_t sig_bytes = (size_t)9 * NP * 4;   // 1.81 MB
    const size_t need4 = 8192 + (size_t)36 * NHW * 4 + sig_bytes;   // ~30.7 MB
    hipMemsetAsync(d_ws, 0, 8192, stream);

    if (ws_size >= need4) {
        float* sig_even = P + (size_t)36 * NHW;
        conv_2deep_kernel<4><<<1568, 256, 0, stream>>>(x, wgt, P);
        merge_stats_kernel<4><<<dim3(196, 9), 256, 0, stream>>>(P, stats, sig_even);
        apply_kernel<<<896, 256, 0, stream>>>(x, sig_even, gamma, beta, stats, out);
    } else {
        float* sig_even = P + (size_t)18 * NHW;
        conv_2deep_kernel<2><<<784, 256, 0, stream>>>(x, wgt, P);
        merge_stats_kernel<2><<<dim3(196, 9), 256, 0, stream>>>(P, stats, sig_even);
        apply_kernel<<<896, 256, 0, stream>>>(x, sig_even, gamma, beta, stats, out);
    }
}